// Round 11
// baseline (384.073 us; speedup 1.0000x reference)
//
#include <hip/hip_runtime.h>
#include <cstdint>

#define TPB 256
typedef __attribute__((ext_vector_type(4))) float f4;

// ---------------------------------------------------------------------------
// Workspace layout (floats):
//   Y     @   512 (512)    C1IN = [Y|Z] @ 512 (1560)
//   Z     @  1024 (1048)
//   C1H   @  2072 (1600)
//   OUT12 @  3672 (4096)   [out1 | out2]
//   A1H   @  7768 (4096)
//   C2H   @ 11864 (4096)
//   OUT34 @ 15960 (8192)   [out3 | out4]
//   A2H   @ 24152 (4096)
//   NTH   @ 28248 (8192)   (unused since nt fusion; still zeroed)
//   OUT6  @ 36440 (14336)  [out5 | out3copy | out1copy]
//   M2H   @ 50776 (8192)
//   HBUF  @ 58968 (8192)
//   M3H1  @ 67160 (512)    (unused since tail fusion; still zeroed)
//   end   @ 67928
// Zero range (atomic-accumulated buffers): [2072, 67928)
// ---------------------------------------------------------------------------

__global__ __launch_bounds__(TPB) void stage1_kernel(
    const float* __restrict__ center, const float* __restrict__ corner,
    const float* __restrict__ normal,
    const float* __restrict__ spW1, const float* __restrict__ spb1,
    const float* __restrict__ spW2, const float* __restrict__ spb2,
    const float* __restrict__ Wc, const float* __restrict__ bc,
    const float* __restrict__ W3, const float* __restrict__ b3,
    const float* __restrict__ W4, const float* __restrict__ b4,
    const float* __restrict__ kck,
    const float* __restrict__ stW1, const float* __restrict__ stb1,
    const float* __restrict__ stW2, const float* __restrict__ stb2,
    float* __restrict__ ws) {
    int tid = threadIdx.x;
    int b = blockIdx.x;
    if (b < 8) {
        // ---- one face per block: FRC conv+mlp, kernel correlation, st MLP
        int f = b;
        __shared__ float sc[9], sn[3], sm[32], shh[64], sf[131], sh2[131];
        if (tid < 9) sc[tid] = corner[f * 9 + tid];
        if (tid < 3) { sn[tid] = normal[f * 3 + tid]; sf[tid] = normal[f * 3 + tid]; }
        __syncthreads();
        if (tid < 32) {                       // conv over 3 corner pairs, mean
            float acc = 0.f;
            for (int p = 0; p < 3; ++p) {
                const float* a  = &sc[3 * p];
                const float* b2 = &sc[3 * ((p + 1) % 3)];
                float d = bc[tid];
                for (int k = 0; k < 3; ++k)
                    d += a[k] * Wc[tid * 6 + k] + b2[k] * Wc[tid * 6 + 3 + k];
                acc += d;
            }
            sm[tid] = acc * (1.f / 3.f);
        }
        __syncthreads();
        if (tid < 64) {                       // frc hidden (32 -> 64), relu
            float h = b3[tid];
            for (int o = 0; o < 32; ++o) h = fmaf(sm[o], W3[o * 64 + tid], h);
            shh[tid] = fmaxf(h, 0.f);
        }
        if (tid < 64) {                       // kernel correlation -> sf[3+tid]
            float s = 0.f;
            for (int l = 0; l < 4; ++l) {
                float dx = sn[0] - kck[(tid * 4 + l) * 3 + 0];
                float dy = sn[1] - kck[(tid * 4 + l) * 3 + 1];
                float dz = sn[2] - kck[(tid * 4 + l) * 3 + 2];
                s += expf(-(dx * dx + dy * dy + dz * dz));
            }
            sf[3 + tid] = s * (1.f / 32.f);
        }
        __syncthreads();
        if (tid < 64) {                       // frc out (64 -> 64) -> sf[67+tid]
            float v = b4[tid];
            for (int k = 0; k < 64; ++k) v = fmaf(shh[k], W4[k * 64 + tid], v);
            sf[67 + tid] = v;
        }
        __syncthreads();
        if (tid < 131) {                      // st hidden, relu
            float a = stb1[tid];
            for (int k = 0; k < 131; ++k) a = fmaf(sf[k], stW1[k * 131 + tid], a);
            sh2[tid] = fmaxf(a, 0.f);
        }
        __syncthreads();
        if (tid < 131) {                      // st out -> Z
            float a = stb2[tid];
            for (int k = 0; k < 131; ++k) a = fmaf(sh2[k], stW2[k * 131 + tid], a);
            ws[1024 + f * 131 + tid] = a;
        }
    } else if (b < 12) {
        // ---- spatial chain: T1 = relu(center@spW1+b1) in LDS; y = T1@spW2+b2
        int bs = b - 8;
        __shared__ float sctr[24], st1[512];
        if (tid < 24) sctr[tid] = center[tid];
        __syncthreads();
        for (int j = tid; j < 512; j += TPB) {
            float a = spb1[j];
            for (int i = 0; i < 24; ++i) a = fmaf(sctr[i], spW1[i * 512 + j], a);
            st1[j] = fmaxf(a, 0.f);
        }
        __syncthreads();
        if (tid < 128) {
            int j = bs * 128 + tid;
            float a = spb2[j];
            for (int k = 0; k < 512; ++k) a = fmaf(st1[k], spW2[k * 512 + j], a);
            ws[512 + j] = a;                  // Y, direct write
        }
    } else {
        // ---- zero the atomic-accumulated region [2072, 67928)
        int zb = b - 12;                      // 0..31
        f4 z4 = {0.f, 0.f, 0.f, 0.f};
        f4* p = (f4*)(ws + 2072);
        int n4 = (67928 - 2072) / 4;          // 16464
        for (int i = zb * TPB + tid; i < n4; i += 32 * TPB) p[i] = z4;
    }
}

// ---------------------------------------------------------------------------
// Multi-GEMV (proven R9/R10 body): split-K, HW f32 atomics onto zeroed bufs,
// bias in ci==0 chunk, fused relu/agg/maxpool staging, op5 = relu-sparse
// (deterministic ballot compaction), nt=1 = nontemporal weight stream.
// ---------------------------------------------------------------------------
struct Desc {
    const float* x; const float* W; float* out; const float* bias;
    const int* nb;
    int in_dim, out_dim, chunk, ntile, nchunk, nvec, xs, os;
    int op;        // 0 direct, 1 relu-in, 2 agg, 3 maxpool8, 4 copy, 5 relu-sparse
    int aggdim;
    int nt;
    int nblocks;
};
struct Descs { Desc d[3]; int nd; };

__global__ __launch_bounds__(TPB) void mg_kernel(Descs D) {
    int bid = blockIdx.x;
    int di = 0;
    while (di + 1 < D.nd && bid >= D.d[di].nblocks) { bid -= D.d[di].nblocks; ++di; }
    Desc d = D.d[di];
    int tid = threadIdx.x;
    if (d.op == 4) {                          // copy
        int i = bid * TPB + tid;
        int n4 = d.in_dim >> 2;
        if (i < n4) ((f4*)d.out)[i] = ((const f4*)d.x)[i];
        return;
    }
    __shared__ float sx[512];
    __shared__ float sval[512];
    __shared__ unsigned short sidx[512];
    __shared__ int segc[10];
    int per = d.ntile * d.nchunk;
    int vec = bid / per;
    int r = bid - vec * per;
    int ci = r / d.ntile;
    int tile = r - ci * d.ntile;
    const float* x = d.x + (size_t)vec * d.xs;
    float* out = d.out + (size_t)vec * d.os;
    int row0 = ci * d.chunk;
    int rows = min(d.chunk, d.in_dim - row0);
    for (int t = tid; t < rows; t += TPB) {
        int idx = row0 + t;
        float v;
        if (d.op == 2) {
            int i = idx / d.aggdim, k = idx - i * d.aggdim;
            const int* nb = d.nb + i * 3;
            v = 0.25f * (x[i * d.aggdim + k] + x[nb[0] * d.aggdim + k] +
                         x[nb[1] * d.aggdim + k] + x[nb[2] * d.aggdim + k]);
        } else if (d.op == 3) {
            v = x[idx];
#pragma unroll
            for (int f = 1; f < 8; ++f) v = fmaxf(v, x[f * d.in_dim + idx]);
        } else {
            v = x[idx];
            if (d.op == 1 || d.op == 5) v = fmaxf(v, 0.f);
        }
        sx[t] = v;
    }
    __syncthreads();

    if (d.op == 5) {
        // ---- deterministic ordered compaction of nonzero rows ----
        int wave = tid >> 6, lane = tid & 63;
        int nseg = (rows + 63) >> 6;
        for (int s = wave; s < nseg; s += 4) {
            int t = s * 64 + lane;
            bool p = (t < rows) && (sx[t] > 0.f);
            unsigned long long m = __ballot(p);
            if (lane == 0) segc[s] = __popcll(m);
        }
        __syncthreads();
        if (tid == 0) {
            int acc = 0;
            for (int s = 0; s < nseg; ++s) { int c = segc[s]; segc[s] = acc; acc += c; }
            segc[nseg] = acc;
        }
        __syncthreads();
        for (int s = wave; s < nseg; s += 4) {
            int t = s * 64 + lane;
            bool p = (t < rows) && (sx[t] > 0.f);
            unsigned long long m = __ballot(p);
            int rk = __popcll(m & ((1ull << lane) - 1ull));
            if (p) {
                int o = segc[s] + rk;
                sval[o] = sx[t];
                sidx[o] = (unsigned short)t;
            }
        }
        __syncthreads();
        int cnt = segc[nseg];
        int j = tile * (TPB * 4) + tid * 4;
        if (j >= d.out_dim) return;
        const float* wb = d.W + j;
        float ax = 0.f, ay = 0.f, az = 0.f, aw = 0.f;
        if (d.nt) {
#pragma unroll 8
            for (int t = 0; t < cnt; ++t) {
                float xv = sval[t];
                f4 w = __builtin_nontemporal_load(
                    (const f4*)(wb + (size_t)(row0 + (int)sidx[t]) * d.out_dim));
                ax = fmaf(xv, w[0], ax); ay = fmaf(xv, w[1], ay);
                az = fmaf(xv, w[2], az); aw = fmaf(xv, w[3], aw);
            }
        } else {
#pragma unroll 8
            for (int t = 0; t < cnt; ++t) {
                float xv = sval[t];
                f4 w = *(const f4*)(wb + (size_t)(row0 + (int)sidx[t]) * d.out_dim);
                ax = fmaf(xv, w[0], ax); ay = fmaf(xv, w[1], ay);
                az = fmaf(xv, w[2], az); aw = fmaf(xv, w[3], aw);
            }
        }
        if (ci == 0 && d.bias) {
            ax += d.bias[j]; ay += d.bias[j + 1];
            az += d.bias[j + 2]; aw += d.bias[j + 3];
        }
        unsafeAtomicAdd(&out[j + 0], ax);
        unsafeAtomicAdd(&out[j + 1], ay);
        unsafeAtomicAdd(&out[j + 2], az);
        unsafeAtomicAdd(&out[j + 3], aw);
        return;
    }

    int j = tile * (TPB * 4) + tid * 4;
    if (j >= d.out_dim) return;
    const float* wp = d.W + (size_t)row0 * d.out_dim + j;
    float ax = 0.f, ay = 0.f, az = 0.f, aw = 0.f;
    if (d.nt) {
#pragma unroll 16
        for (int t = 0; t < rows; ++t) {
            f4 w = __builtin_nontemporal_load((const f4*)wp);
            float xv = sx[t];
            ax = fmaf(xv, w[0], ax); ay = fmaf(xv, w[1], ay);
            az = fmaf(xv, w[2], az); aw = fmaf(xv, w[3], aw);
            wp += d.out_dim;
        }
    } else {
#pragma unroll 16
        for (int t = 0; t < rows; ++t) {
            f4 w = *(const f4*)wp;
            float xv = sx[t];
            ax = fmaf(xv, w[0], ax); ay = fmaf(xv, w[1], ay);
            az = fmaf(xv, w[2], az); aw = fmaf(xv, w[3], aw);
            wp += d.out_dim;
        }
    }
    if (ci == 0 && d.bias) {
        ax += d.bias[j]; ay += d.bias[j + 1]; az += d.bias[j + 2]; aw += d.bias[j + 3];
    }
    unsafeAtomicAdd(&out[j + 0], ax);
    unsafeAtomicAdd(&out[j + 1], ay);
    unsafeAtomicAdd(&out[j + 2], az);
    unsafeAtomicAdd(&out[j + 3], aw);
}

// ---------------------------------------------------------------------------
// Fused nt chain: per-face block computes out5[f] = relu(x[f]@W1+b1)@W2+b2
// entirely in LDS (weights L2-resident across the 8 blocks); blocks 8..13
// perform the two OUT6 copies (out3 -> +8192, out1 -> +12288). Direct writes.
// ---------------------------------------------------------------------------
__global__ __launch_bounds__(TPB) void ntf_kernel(
    const float* __restrict__ OUT34, const float* __restrict__ OUT12,
    const float* __restrict__ W1, const float* __restrict__ b1,
    const float* __restrict__ W2, const float* __restrict__ b2,
    float* __restrict__ OUT6) {
    int b = blockIdx.x, tid = threadIdx.x;
    if (b >= 8) {
        if (b < 12) {                         // copy out3 (4096 floats)
            int i = (b - 8) * TPB + tid;
            ((f4*)(OUT6 + 8192))[i] = ((const f4*)OUT34)[i];
        } else {                              // copy out1 (2048 floats)
            int i = (b - 12) * TPB + tid;
            ((f4*)(OUT6 + 12288))[i] = ((const f4*)OUT12)[i];
        }
        return;
    }
    __shared__ float sx[1024], sh[1024];
    for (int k = tid; k < 1024; k += TPB) sx[k] = OUT34[b * 1024 + k];
    __syncthreads();
    int j = tid * 4;
    float a0 = b1[j], a1 = b1[j + 1], a2 = b1[j + 2], a3 = b1[j + 3];
#pragma unroll 16
    for (int k = 0; k < 1024; ++k) {
        f4 w = *(const f4*)(W1 + (size_t)k * 1024 + j);
        float xv = sx[k];
        a0 = fmaf(xv, w[0], a0); a1 = fmaf(xv, w[1], a1);
        a2 = fmaf(xv, w[2], a2); a3 = fmaf(xv, w[3], a3);
    }
    sh[j] = fmaxf(a0, 0.f); sh[j + 1] = fmaxf(a1, 0.f);
    sh[j + 2] = fmaxf(a2, 0.f); sh[j + 3] = fmaxf(a3, 0.f);
    __syncthreads();
    float c0 = b2[j], c1 = b2[j + 1], c2 = b2[j + 2], c3 = b2[j + 3];
#pragma unroll 16
    for (int k = 0; k < 1024; ++k) {
        f4 w = *(const f4*)(W2 + (size_t)k * 1024 + j);
        float xv = sh[k];
        c0 = fmaf(xv, w[0], c0); c1 = fmaf(xv, w[1], c1);
        c2 = fmaf(xv, w[2], c2); c3 = fmaf(xv, w[3], c3);
    }
    OUT6[b * 1024 + j] = c0;     OUT6[b * 1024 + j + 1] = c1;
    OUT6[b * 1024 + j + 2] = c2; OUT6[b * 1024 + j + 3] = c3;
}

// ---------------------------------------------------------------------------
// Fused m3 tail: each of 40 blocks recomputes maxpool(HBUF) -> g, M3H1 =
// relu(g@W1+b1), M3H2 = relu(M3H1@W2+b2), then its logit via deterministic
// tree reduction. W1 (2 MB) / W2 (0.5 MB) are L2-resident across blocks.
// ---------------------------------------------------------------------------
__global__ __launch_bounds__(TPB) void tail2_kernel(
    const float* __restrict__ hbuf,
    const float* __restrict__ W1, const float* __restrict__ b1,
    const float* __restrict__ W2, const float* __restrict__ b2,
    const float* __restrict__ W3, const float* __restrict__ b3,
    float* __restrict__ out) {
    __shared__ float g[1024], h1[512], red[256];
    int tid = threadIdx.x, j = blockIdx.x;
    for (int k = tid; k < 1024; k += TPB) {
        float m = hbuf[k];
#pragma unroll
        for (int f = 1; f < 8; ++f) m = fmaxf(m, hbuf[f * 1024 + k]);
        g[k] = m;
    }
    __syncthreads();
    float a0 = b1[tid], a1 = b1[tid + 256];
#pragma unroll 8
    for (int k = 0; k < 1024; ++k) {
        float xv = g[k];
        a0 = fmaf(xv, W1[(size_t)k * 512 + tid], a0);
        a1 = fmaf(xv, W1[(size_t)k * 512 + tid + 256], a1);
    }
    h1[tid] = fmaxf(a0, 0.f); h1[tid + 256] = fmaxf(a1, 0.f);
    __syncthreads();
    float c0 = b2[tid];
#pragma unroll 8
    for (int k = 0; k < 512; ++k) c0 = fmaf(h1[k], W2[k * 256 + tid], c0);
    c0 = fmaxf(c0, 0.f);
    red[tid] = c0 * W3[tid * 40 + j];
    __syncthreads();
    for (int s = 128; s > 0; s >>= 1) {
        if (tid < s) red[tid] += red[tid + s];
        __syncthreads();
    }
    if (tid == 0) out[j] = red[0] + b3[j];
}

// ---------------------------------------------------------------------------
static Desc gemv_desc(const float* x, const float* W, float* out, const float* bias,
                      int in, int outd, int chunk, int op,
                      int nvec = 1, int xs = 0, int os = 0,
                      const int* nb = nullptr, int aggdim = 0, int nt = 0) {
    Desc d{};
    d.x = x; d.W = W; d.out = out; d.bias = bias; d.nb = nb;
    d.in_dim = in; d.out_dim = outd; d.chunk = chunk;
    d.ntile = (outd + TPB * 4 - 1) / (TPB * 4);
    d.nchunk = (in + chunk - 1) / chunk;
    d.nvec = nvec; d.xs = xs; d.os = os;
    d.op = op; d.aggdim = aggdim; d.nt = nt;
    d.nblocks = d.ntile * d.nchunk * nvec;
    return d;
}
static void mg1(hipStream_t s, Desc a) {
    Descs D{}; D.d[0] = a; D.nd = 1;
    mg_kernel<<<a.nblocks, TPB, 0, s>>>(D);
}
static void mg2(hipStream_t s, Desc a, Desc b) {
    Descs D{}; D.d[0] = a; D.d[1] = b; D.nd = 2;
    mg_kernel<<<a.nblocks + b.nblocks, TPB, 0, s>>>(D);
}

extern "C" void kernel_launch(void* const* d_in, const int* in_sizes, int n_in,
                              void* d_out, int out_size, void* d_ws, size_t ws_size,
                              hipStream_t stream) {
    const float* center    = (const float*)d_in[0];
    const float* corner    = (const float*)d_in[1];
    const float* normal    = (const float*)d_in[2];
    const int*   neighbour = (const int*)  d_in[3];
    const float* sp_W1 = (const float*)d_in[4];
    const float* sp_b1 = (const float*)d_in[5];
    const float* sp_W2 = (const float*)d_in[6];
    const float* sp_b2 = (const float*)d_in[7];
    const float* frc_Wc = (const float*)d_in[8];
    const float* frc_bc = (const float*)d_in[9];
    const float* frc_W3 = (const float*)d_in[10];
    const float* frc_b3 = (const float*)d_in[11];
    const float* frc_W4 = (const float*)d_in[12];
    const float* frc_b4 = (const float*)d_in[13];
    const float* kc_kernel = (const float*)d_in[14];
    const float* st_W1 = (const float*)d_in[15];
    const float* st_b1 = (const float*)d_in[16];
    const float* st_W2 = (const float*)d_in[17];
    const float* st_b2 = (const float*)d_in[18];
    const float* c1_W1 = (const float*)d_in[19];
    const float* c1_b1 = (const float*)d_in[20];
    const float* c1_W2 = (const float*)d_in[21];
    const float* c1_b2 = (const float*)d_in[22];
    const float* a1_W3 = (const float*)d_in[23];
    const float* a1_b3 = (const float*)d_in[24];
    const float* a1_W4 = (const float*)d_in[25];
    const float* a1_b4 = (const float*)d_in[26];
    const float* c2_W1 = (const float*)d_in[27];
    const float* c2_b1 = (const float*)d_in[28];
    const float* c2_W2 = (const float*)d_in[29];
    const float* c2_b2 = (const float*)d_in[30];
    const float* a2_W3 = (const float*)d_in[31];
    const float* a2_b3 = (const float*)d_in[32];
    const float* a2_W4 = (const float*)d_in[33];
    const float* a2_b4 = (const float*)d_in[34];
    const float* nt_W1 = (const float*)d_in[35];
    const float* nt_b1 = (const float*)d_in[36];
    const float* nt_W2 = (const float*)d_in[37];
    const float* nt_b2 = (const float*)d_in[38];
    const float* m2_W1 = (const float*)d_in[39];
    const float* m2_b1 = (const float*)d_in[40];
    const float* m2_W2 = (const float*)d_in[41];
    const float* m2_b2 = (const float*)d_in[42];
    const float* m3_W1 = (const float*)d_in[43];
    const float* m3_b1 = (const float*)d_in[44];
    const float* m3_W2 = (const float*)d_in[45];
    const float* m3_b2 = (const float*)d_in[46];
    const float* m3_W3 = (const float*)d_in[47];
    const float* m3_b3 = (const float*)d_in[48];

    float* ws = (float*)d_ws;
    float* C1IN  = ws + 512;           // [Y(512) | Z(1048)]
    float* Z     = ws + 1024;
    float* C1H   = ws + 2072;
    float* OUT12 = ws + 3672;          // [out1 | out2]
    float* A1H   = ws + 7768;
    float* C2H   = ws + 11864;
    float* OUT34 = ws + 15960;         // [out3 | out4]
    float* A2H   = ws + 24152;
    float* OUT6  = ws + 36440;         // [out5 | out3c | out1c]
    float* M2H   = ws + 50776;
    float* HBUF  = ws + 58968;

    // L1: faces + spatial chain + zeroing
    stage1_kernel<<<44, TPB, 0, stream>>>(center, corner, normal,
        sp_W1, sp_b1, sp_W2, sp_b2, frc_Wc, frc_bc, frc_W3, frc_b3,
        frc_W4, frc_b4, kc_kernel, st_W1, st_b1, st_W2, st_b2, ws);

    // L2: c1_W1 (x=[y|z]) + a1_W3 (agg1 inline from Z)  [NT]
    mg2(stream,
        gemv_desc(C1IN, c1_W1, C1H, c1_b1, 1560, 1600, 26, 0,
                  1, 0, 0, nullptr, 0, 1),
        gemv_desc(Z, a1_W3, A1H, a1_b3, 1048, 4096, 17, 2,
                  1, 0, 0, neighbour, 131, 1));
    // L3: c1_W2 (sparse) + a1_W4 (sparse)  [NT]
    mg2(stream,
        gemv_desc(C1H, c1_W2, OUT12, c1_b2, 1600, 2048, 28, 5,
                  1, 0, 0, nullptr, 0, 1),
        gemv_desc(A1H, a1_W4, OUT12 + 2048, a1_b4, 4096, 2048, 64, 5,
                  1, 0, 0, nullptr, 0, 1));
    // L4: c2_W1 + a2_W3 (agg2 inline from out2)  [NT]
    mg2(stream,
        gemv_desc(OUT12, c2_W1, C2H, c2_b1, 4096, 4096, 64, 0,
                  1, 0, 0, nullptr, 0, 1),
        gemv_desc(OUT12 + 2048, a2_W3, A2H, a2_b3, 2048, 4096, 32, 2,
                  1, 0, 0, neighbour, 256, 1));
    // L5: c2_W2 (sparse) + a2_W4 (sparse)  [NT]
    mg2(stream,
        gemv_desc(C2H, c2_W2, OUT34, c2_b2, 4096, 4096, 64, 5,
                  1, 0, 0, nullptr, 0, 1),
        gemv_desc(A2H, a2_W4, OUT34 + 4096, a2_b4, 4096, 4096, 64, 5,
                  1, 0, 0, nullptr, 0, 1));
    // L6: fused nt chain per face + OUT6 copies (14 blocks)
    ntf_kernel<<<14, TPB, 0, stream>>>(OUT34, OUT12, nt_W1, nt_b1,
                                       nt_W2, nt_b2, OUT6);
    // L7: m2_W1 (470 MB, dense, NT)
    mg1(stream, gemv_desc(OUT6, m2_W1, M2H, m2_b1, 14336, 8192, 448, 0,
                          1, 0, 0, nullptr, 0, 1));
    // L8: m2_W2 (268 MB, relu-sparse, NT)
    mg1(stream, gemv_desc(M2H, m2_W2, HBUF, m2_b2, 8192, 8192, 256, 5,
                          1, 0, 0, nullptr, 0, 1));
    // L9: fused maxpool + m3_W1 + m3_W2 + head (40 blocks)
    tail2_kernel<<<40, TPB, 0, stream>>>(HBUF, m3_W1, m3_b1, m3_W2, m3_b2,
                                         m3_W3, m3_b3, (float*)d_out);
}

// Round 12
// 307.752 us; speedup vs baseline: 1.2480x; 1.2480x over previous
//
#include <hip/hip_runtime.h>
#include <cstdint>

#define TPB 256
typedef __attribute__((ext_vector_type(4))) float f4;

// ---------------------------------------------------------------------------
// Workspace layout (floats):
//   Y     @   512 (512)    C1IN = [Y|Z] @ 512 (1560)
//   Z     @  1024 (1048)
//   C1H   @  2072 (1600)
//   OUT12 @  3672 (4096)   [out1 | out2]
//   A1H   @  7768 (4096)
//   C2H   @ 11864 (4096)
//   OUT34 @ 15960 (8192)   [out3 | out4]
//   A2H   @ 24152 (4096)
//   NTH   @ 28248 (8192)
//   OUT6  @ 36440 (14336)  [out5 | out3copy | out1copy]
//   M2H   @ 50776 (8192)
//   HBUF  @ 58968 (8192)
//   M3H1  @ 67160 (512)
//   end   @ 67928
// Zero range (atomic-accumulated buffers): [2072, 67928)
// ---------------------------------------------------------------------------

__global__ __launch_bounds__(TPB) void stage1_kernel(
    const float* __restrict__ center, const float* __restrict__ corner,
    const float* __restrict__ normal,
    const float* __restrict__ spW1, const float* __restrict__ spb1,
    const float* __restrict__ spW2, const float* __restrict__ spb2,
    const float* __restrict__ Wc, const float* __restrict__ bc,
    const float* __restrict__ W3, const float* __restrict__ b3,
    const float* __restrict__ W4, const float* __restrict__ b4,
    const float* __restrict__ kck,
    const float* __restrict__ stW1, const float* __restrict__ stb1,
    const float* __restrict__ stW2, const float* __restrict__ stb2,
    float* __restrict__ ws) {
    int tid = threadIdx.x;
    int b = blockIdx.x;
    if (b < 8) {
        // ---- one face per block: FRC conv+mlp, kernel correlation, st MLP
        int f = b;
        __shared__ float sc[9], sn[3], sm[32], shh[64], sf[131], sh2[131];
        if (tid < 9) sc[tid] = corner[f * 9 + tid];
        if (tid < 3) { sn[tid] = normal[f * 3 + tid]; sf[tid] = normal[f * 3 + tid]; }
        __syncthreads();
        if (tid < 32) {                       // conv over 3 corner pairs, mean
            float acc = 0.f;
            for (int p = 0; p < 3; ++p) {
                const float* a  = &sc[3 * p];
                const float* b2 = &sc[3 * ((p + 1) % 3)];
                float d = bc[tid];
                for (int k = 0; k < 3; ++k)
                    d += a[k] * Wc[tid * 6 + k] + b2[k] * Wc[tid * 6 + 3 + k];
                acc += d;
            }
            sm[tid] = acc * (1.f / 3.f);
        }
        __syncthreads();
        if (tid < 64) {                       // frc hidden (32 -> 64), relu
            float h = b3[tid];
            for (int o = 0; o < 32; ++o) h = fmaf(sm[o], W3[o * 64 + tid], h);
            shh[tid] = fmaxf(h, 0.f);
        }
        if (tid < 64) {                       // kernel correlation -> sf[3+tid]
            float s = 0.f;
            for (int l = 0; l < 4; ++l) {
                float dx = sn[0] - kck[(tid * 4 + l) * 3 + 0];
                float dy = sn[1] - kck[(tid * 4 + l) * 3 + 1];
                float dz = sn[2] - kck[(tid * 4 + l) * 3 + 2];
                s += expf(-(dx * dx + dy * dy + dz * dz));
            }
            sf[3 + tid] = s * (1.f / 32.f);
        }
        __syncthreads();
        if (tid < 64) {                       // frc out (64 -> 64) -> sf[67+tid]
            float v = b4[tid];
            for (int k = 0; k < 64; ++k) v = fmaf(shh[k], W4[k * 64 + tid], v);
            sf[67 + tid] = v;
        }
        __syncthreads();
        if (tid < 131) {                      // st hidden, relu
            float a = stb1[tid];
            for (int k = 0; k < 131; ++k) a = fmaf(sf[k], stW1[k * 131 + tid], a);
            sh2[tid] = fmaxf(a, 0.f);
        }
        __syncthreads();
        if (tid < 131) {                      // st out -> Z
            float a = stb2[tid];
            for (int k = 0; k < 131; ++k) a = fmaf(sh2[k], stW2[k * 131 + tid], a);
            ws[1024 + f * 131 + tid] = a;
        }
    } else if (b < 12) {
        // ---- spatial chain: T1 = relu(center@spW1+b1) in LDS; y = T1@spW2+b2
        int bs = b - 8;
        __shared__ float sctr[24], st1[512];
        if (tid < 24) sctr[tid] = center[tid];
        __syncthreads();
        for (int j = tid; j < 512; j += TPB) {
            float a = spb1[j];
            for (int i = 0; i < 24; ++i) a = fmaf(sctr[i], spW1[i * 512 + j], a);
            st1[j] = fmaxf(a, 0.f);
        }
        __syncthreads();
        if (tid < 128) {
            int j = bs * 128 + tid;
            float a = spb2[j];
            for (int k = 0; k < 512; ++k) a = fmaf(st1[k], spW2[k * 512 + j], a);
            ws[512 + j] = a;                  // Y, direct write
        }
    } else {
        // ---- zero the atomic-accumulated region [2072, 67928)
        int zb = b - 12;                      // 0..31
        f4 z4 = {0.f, 0.f, 0.f, 0.f};
        f4* p = (f4*)(ws + 2072);
        int n4 = (67928 - 2072) / 4;          // 16464
        for (int i = zb * TPB + tid; i < n4; i += 32 * TPB) p[i] = z4;
    }
}

// ---------------------------------------------------------------------------
// Multi-GEMV (proven R10 body): split-K, HW f32 atomics onto zeroed bufs,
// bias in ci==0 chunk, fused relu/agg/maxpool staging, op5 = relu-sparse
// (deterministic ballot compaction), nt=1 = nontemporal weight stream.
// ---------------------------------------------------------------------------
struct Desc {
    const float* x; const float* W; float* out; const float* bias;
    const int* nb;
    int in_dim, out_dim, chunk, ntile, nchunk, nvec, xs, os;
    int op;        // 0 direct, 1 relu-in, 2 agg, 3 maxpool8, 4 copy, 5 relu-sparse
    int aggdim;
    int nt;
    int nblocks;
};
struct Descs { Desc d[3]; int nd; };

__global__ __launch_bounds__(TPB) void mg_kernel(Descs D) {
    int bid = blockIdx.x;
    int di = 0;
    while (di + 1 < D.nd && bid >= D.d[di].nblocks) { bid -= D.d[di].nblocks; ++di; }
    Desc d = D.d[di];
    int tid = threadIdx.x;
    if (d.op == 4) {                          // copy
        int i = bid * TPB + tid;
        int n4 = d.in_dim >> 2;
        if (i < n4) ((f4*)d.out)[i] = ((const f4*)d.x)[i];
        return;
    }
    __shared__ float sx[512];
    __shared__ float sval[512];
    __shared__ unsigned short sidx[512];
    __shared__ int segc[10];
    int per = d.ntile * d.nchunk;
    int vec = bid / per;
    int r = bid - vec * per;
    int ci = r / d.ntile;
    int tile = r - ci * d.ntile;
    const float* x = d.x + (size_t)vec * d.xs;
    float* out = d.out + (size_t)vec * d.os;
    int row0 = ci * d.chunk;
    int rows = min(d.chunk, d.in_dim - row0);
    for (int t = tid; t < rows; t += TPB) {
        int idx = row0 + t;
        float v;
        if (d.op == 2) {
            int i = idx / d.aggdim, k = idx - i * d.aggdim;
            const int* nb = d.nb + i * 3;
            v = 0.25f * (x[i * d.aggdim + k] + x[nb[0] * d.aggdim + k] +
                         x[nb[1] * d.aggdim + k] + x[nb[2] * d.aggdim + k]);
        } else if (d.op == 3) {
            v = x[idx];
#pragma unroll
            for (int f = 1; f < 8; ++f) v = fmaxf(v, x[f * d.in_dim + idx]);
        } else {
            v = x[idx];
            if (d.op == 1 || d.op == 5) v = fmaxf(v, 0.f);
        }
        sx[t] = v;
    }
    __syncthreads();

    if (d.op == 5) {
        // ---- deterministic ordered compaction of nonzero rows ----
        int wave = tid >> 6, lane = tid & 63;
        int nseg = (rows + 63) >> 6;
        for (int s = wave; s < nseg; s += 4) {
            int t = s * 64 + lane;
            bool p = (t < rows) && (sx[t] > 0.f);
            unsigned long long m = __ballot(p);
            if (lane == 0) segc[s] = __popcll(m);
        }
        __syncthreads();
        if (tid == 0) {
            int acc = 0;
            for (int s = 0; s < nseg; ++s) { int c = segc[s]; segc[s] = acc; acc += c; }
            segc[nseg] = acc;
        }
        __syncthreads();
        for (int s = wave; s < nseg; s += 4) {
            int t = s * 64 + lane;
            bool p = (t < rows) && (sx[t] > 0.f);
            unsigned long long m = __ballot(p);
            int rk = __popcll(m & ((1ull << lane) - 1ull));
            if (p) {
                int o = segc[s] + rk;
                sval[o] = sx[t];
                sidx[o] = (unsigned short)t;
            }
        }
        __syncthreads();
        int cnt = segc[nseg];
        int j = tile * (TPB * 4) + tid * 4;
        if (j >= d.out_dim) return;
        const float* wb = d.W + j;
        float ax = 0.f, ay = 0.f, az = 0.f, aw = 0.f;
        if (d.nt) {
#pragma unroll 8
            for (int t = 0; t < cnt; ++t) {
                float xv = sval[t];
                f4 w = __builtin_nontemporal_load(
                    (const f4*)(wb + (size_t)(row0 + (int)sidx[t]) * d.out_dim));
                ax = fmaf(xv, w[0], ax); ay = fmaf(xv, w[1], ay);
                az = fmaf(xv, w[2], az); aw = fmaf(xv, w[3], aw);
            }
        } else {
#pragma unroll 8
            for (int t = 0; t < cnt; ++t) {
                float xv = sval[t];
                f4 w = *(const f4*)(wb + (size_t)(row0 + (int)sidx[t]) * d.out_dim);
                ax = fmaf(xv, w[0], ax); ay = fmaf(xv, w[1], ay);
                az = fmaf(xv, w[2], az); aw = fmaf(xv, w[3], aw);
            }
        }
        if (ci == 0 && d.bias) {
            ax += d.bias[j]; ay += d.bias[j + 1];
            az += d.bias[j + 2]; aw += d.bias[j + 3];
        }
        unsafeAtomicAdd(&out[j + 0], ax);
        unsafeAtomicAdd(&out[j + 1], ay);
        unsafeAtomicAdd(&out[j + 2], az);
        unsafeAtomicAdd(&out[j + 3], aw);
        return;
    }

    int j = tile * (TPB * 4) + tid * 4;
    if (j >= d.out_dim) return;
    const float* wp = d.W + (size_t)row0 * d.out_dim + j;
    float ax = 0.f, ay = 0.f, az = 0.f, aw = 0.f;
    if (d.nt) {
#pragma unroll 16
        for (int t = 0; t < rows; ++t) {
            f4 w = __builtin_nontemporal_load((const f4*)wp);
            float xv = sx[t];
            ax = fmaf(xv, w[0], ax); ay = fmaf(xv, w[1], ay);
            az = fmaf(xv, w[2], az); aw = fmaf(xv, w[3], aw);
            wp += d.out_dim;
        }
    } else {
#pragma unroll 16
        for (int t = 0; t < rows; ++t) {
            f4 w = *(const f4*)wp;
            float xv = sx[t];
            ax = fmaf(xv, w[0], ax); ay = fmaf(xv, w[1], ay);
            az = fmaf(xv, w[2], az); aw = fmaf(xv, w[3], aw);
            wp += d.out_dim;
        }
    }
    if (ci == 0 && d.bias) {
        ax += d.bias[j]; ay += d.bias[j + 1]; az += d.bias[j + 2]; aw += d.bias[j + 3];
    }
    unsafeAtomicAdd(&out[j + 0], ax);
    unsafeAtomicAdd(&out[j + 1], ay);
    unsafeAtomicAdd(&out[j + 2], az);
    unsafeAtomicAdd(&out[j + 3], aw);
}

// ---------------------------------------------------------------------------
// Fused m3 tail: each of 40 blocks recomputes maxpool(HBUF) -> g, M3H1 =
// relu(g@W1+b1), M3H2 = relu(M3H1@W2+b2), then its logit via deterministic
// tree reduction. W1 (2 MB) / W2 (0.5 MB) are L2-resident across blocks.
// ---------------------------------------------------------------------------
__global__ __launch_bounds__(TPB) void tail2_kernel(
    const float* __restrict__ hbuf,
    const float* __restrict__ W1, const float* __restrict__ b1,
    const float* __restrict__ W2, const float* __restrict__ b2,
    const float* __restrict__ W3, const float* __restrict__ b3,
    float* __restrict__ out) {
    __shared__ float g[1024], h1[512], red[256];
    int tid = threadIdx.x, j = blockIdx.x;
    for (int k = tid; k < 1024; k += TPB) {
        float m = hbuf[k];
#pragma unroll
        for (int f = 1; f < 8; ++f) m = fmaxf(m, hbuf[f * 1024 + k]);
        g[k] = m;
    }
    __syncthreads();
    float a0 = b1[tid], a1 = b1[tid + 256];
#pragma unroll 8
    for (int k = 0; k < 1024; ++k) {
        float xv = g[k];
        a0 = fmaf(xv, W1[(size_t)k * 512 + tid], a0);
        a1 = fmaf(xv, W1[(size_t)k * 512 + tid + 256], a1);
    }
    h1[tid] = fmaxf(a0, 0.f); h1[tid + 256] = fmaxf(a1, 0.f);
    __syncthreads();
    float c0 = b2[tid];
#pragma unroll 8
    for (int k = 0; k < 512; ++k) c0 = fmaf(h1[k], W2[k * 256 + tid], c0);
    c0 = fmaxf(c0, 0.f);
    red[tid] = c0 * W3[tid * 40 + j];
    __syncthreads();
    for (int s = 128; s > 0; s >>= 1) {
        if (tid < s) red[tid] += red[tid + s];
        __syncthreads();
    }
    if (tid == 0) out[j] = red[0] + b3[j];
}

// ---------------------------------------------------------------------------
static Desc gemv_desc(const float* x, const float* W, float* out, const float* bias,
                      int in, int outd, int chunk, int op,
                      int nvec = 1, int xs = 0, int os = 0,
                      const int* nb = nullptr, int aggdim = 0, int nt = 0) {
    Desc d{};
    d.x = x; d.W = W; d.out = out; d.bias = bias; d.nb = nb;
    d.in_dim = in; d.out_dim = outd; d.chunk = chunk;
    d.ntile = (outd + TPB * 4 - 1) / (TPB * 4);
    d.nchunk = (in + chunk - 1) / chunk;
    d.nvec = nvec; d.xs = xs; d.os = os;
    d.op = op; d.aggdim = aggdim; d.nt = nt;
    d.nblocks = d.ntile * d.nchunk * nvec;
    return d;
}
static Desc copy_desc(const float* src, float* dst, int n) {
    Desc d{};
    d.x = src; d.out = dst; d.in_dim = n; d.op = 4;
    d.nblocks = (n / 4 + TPB - 1) / TPB;
    return d;
}
static void mg1(hipStream_t s, Desc a) {
    Descs D{}; D.d[0] = a; D.nd = 1;
    mg_kernel<<<a.nblocks, TPB, 0, s>>>(D);
}
static void mg2(hipStream_t s, Desc a, Desc b) {
    Descs D{}; D.d[0] = a; D.d[1] = b; D.nd = 2;
    mg_kernel<<<a.nblocks + b.nblocks, TPB, 0, s>>>(D);
}
static void mg3(hipStream_t s, Desc a, Desc b, Desc c) {
    Descs D{}; D.d[0] = a; D.d[1] = b; D.d[2] = c; D.nd = 3;
    mg_kernel<<<a.nblocks + b.nblocks + c.nblocks, TPB, 0, s>>>(D);
}

extern "C" void kernel_launch(void* const* d_in, const int* in_sizes, int n_in,
                              void* d_out, int out_size, void* d_ws, size_t ws_size,
                              hipStream_t stream) {
    const float* center    = (const float*)d_in[0];
    const float* corner    = (const float*)d_in[1];
    const float* normal    = (const float*)d_in[2];
    const int*   neighbour = (const int*)  d_in[3];
    const float* sp_W1 = (const float*)d_in[4];
    const float* sp_b1 = (const float*)d_in[5];
    const float* sp_W2 = (const float*)d_in[6];
    const float* sp_b2 = (const float*)d_in[7];
    const float* frc_Wc = (const float*)d_in[8];
    const float* frc_bc = (const float*)d_in[9];
    const float* frc_W3 = (const float*)d_in[10];
    const float* frc_b3 = (const float*)d_in[11];
    const float* frc_W4 = (const float*)d_in[12];
    const float* frc_b4 = (const float*)d_in[13];
    const float* kc_kernel = (const float*)d_in[14];
    const float* st_W1 = (const float*)d_in[15];
    const float* st_b1 = (const float*)d_in[16];
    const float* st_W2 = (const float*)d_in[17];
    const float* st_b2 = (const float*)d_in[18];
    const float* c1_W1 = (const float*)d_in[19];
    const float* c1_b1 = (const float*)d_in[20];
    const float* c1_W2 = (const float*)d_in[21];
    const float* c1_b2 = (const float*)d_in[22];
    const float* a1_W3 = (const float*)d_in[23];
    const float* a1_b3 = (const float*)d_in[24];
    const float* a1_W4 = (const float*)d_in[25];
    const float* a1_b4 = (const float*)d_in[26];
    const float* c2_W1 = (const float*)d_in[27];
    const float* c2_b1 = (const float*)d_in[28];
    const float* c2_W2 = (const float*)d_in[29];
    const float* c2_b2 = (const float*)d_in[30];
    const float* a2_W3 = (const float*)d_in[31];
    const float* a2_b3 = (const float*)d_in[32];
    const float* a2_W4 = (const float*)d_in[33];
    const float* a2_b4 = (const float*)d_in[34];
    const float* nt_W1 = (const float*)d_in[35];
    const float* nt_b1 = (const float*)d_in[36];
    const float* nt_W2 = (const float*)d_in[37];
    const float* nt_b2 = (const float*)d_in[38];
    const float* m2_W1 = (const float*)d_in[39];
    const float* m2_b1 = (const float*)d_in[40];
    const float* m2_W2 = (const float*)d_in[41];
    const float* m2_b2 = (const float*)d_in[42];
    const float* m3_W1 = (const float*)d_in[43];
    const float* m3_b1 = (const float*)d_in[44];
    const float* m3_W2 = (const float*)d_in[45];
    const float* m3_b2 = (const float*)d_in[46];
    const float* m3_W3 = (const float*)d_in[47];
    const float* m3_b3 = (const float*)d_in[48];

    float* ws = (float*)d_ws;
    float* C1IN  = ws + 512;           // [Y(512) | Z(1048)]
    float* Z     = ws + 1024;
    float* C1H   = ws + 2072;
    float* OUT12 = ws + 3672;          // [out1 | out2]
    float* A1H   = ws + 7768;
    float* C2H   = ws + 11864;
    float* OUT34 = ws + 15960;         // [out3 | out4]
    float* A2H   = ws + 24152;
    float* NTH   = ws + 28248;
    float* OUT6  = ws + 36440;         // [out5 | out3c | out1c]
    float* M2H   = ws + 50776;
    float* HBUF  = ws + 58968;

    // L1: faces + spatial chain + zeroing
    stage1_kernel<<<44, TPB, 0, stream>>>(center, corner, normal,
        sp_W1, sp_b1, sp_W2, sp_b2, frc_Wc, frc_bc, frc_W3, frc_b3,
        frc_W4, frc_b4, kc_kernel, st_W1, st_b1, st_W2, st_b2, ws);

    // L2: c1_W1 (x=[y|z]) + a1_W3 (agg1 inline from Z)
    mg2(stream,
        gemv_desc(C1IN, c1_W1, C1H, c1_b1, 1560, 1600, 26, 0),
        gemv_desc(Z, a1_W3, A1H, a1_b3, 1048, 4096, 17, 2, 1, 0, 0, neighbour, 131));
    // L3: c1_W2 (relu-sparse) + a1_W4 (relu-sparse)
    mg2(stream,
        gemv_desc(C1H, c1_W2, OUT12, c1_b2, 1600, 2048, 28, 5),
        gemv_desc(A1H, a1_W4, OUT12 + 2048, a1_b4, 4096, 2048, 64, 5));
    // L4: c2_W1 + a2_W3 (agg2 inline from out2)
    mg2(stream,
        gemv_desc(OUT12, c2_W1, C2H, c2_b1, 4096, 4096, 64, 0),
        gemv_desc(OUT12 + 2048, a2_W3, A2H, a2_b3, 2048, 4096, 32, 2, 1, 0, 0, neighbour, 256));
    // L5: c2_W2 (sparse) + a2_W4 (sparse) + copy out1 -> OUT6 tail
    mg3(stream,
        gemv_desc(C2H, c2_W2, OUT34, c2_b2, 4096, 4096, 64, 5),
        gemv_desc(A2H, a2_W4, OUT34 + 4096, a2_b4, 4096, 4096, 64, 5),
        copy_desc(OUT12, OUT6 + 12288, 2048));
    // L6: nt_W1 (8 faces) + copy out3 -> OUT6 mid
    mg2(stream,
        gemv_desc(OUT34, nt_W1, NTH, nt_b1, 1024, 1024, 64, 0, 8, 1024, 1024),
        copy_desc(OUT34, OUT6 + 8192, 4096));
    // L7: nt_W2 -> out5 (relu-sparse)
    mg1(stream,
        gemv_desc(NTH, nt_W2, OUT6, nt_b2, 1024, 1024, 64, 5, 8, 1024, 1024));
    // L8: m2_W1 (470 MB, dense, nontemporal)
    mg1(stream, gemv_desc(OUT6, m2_W1, M2H, m2_b1, 14336, 8192, 448, 0,
                          1, 0, 0, nullptr, 0, 1));
    // L9: m2_W2 (268 MB, relu-sparse + nontemporal)
    mg1(stream, gemv_desc(M2H, m2_W2, HBUF, m2_b2, 8192, 8192, 256, 5,
                          1, 0, 0, nullptr, 0, 1));
    // L10: fused maxpool + m3_W1 + m3_W2 + head (40 blocks)
    tail2_kernel<<<40, TPB, 0, stream>>>(HBUF, m3_W1, m3_b1, m3_W2, m3_b2,
                                         m3_W3, m3_b3, (float*)d_out);
}

// Round 13
// 262.416 us; speedup vs baseline: 1.4636x; 1.1728x over previous
//
#include <hip/hip_runtime.h>
#include <cstdint>

#define TPB 256
typedef __attribute__((ext_vector_type(4))) float f4;

// ---------------------------------------------------------------------------
// Workspace layout (floats):
//   Y     @   512 (512)    C1IN = [Y|Z] @ 512 (1560)
//   Z     @  1024 (1048)
//   C1H   @  2072 (1600)
//   OUT12 @  3672 (4096)   [out1 | out2]
//   A1H   @  7768 (4096)
//   C2H   @ 11864 (4096)
//   OUT34 @ 15960 (8192)   [out3 | out4]
//   A2H   @ 24152 (4096)
//   NTH   @ 28248 (8192)
//   OUT6  @ 36440 (14336)  [out5 | out3copy | out1copy]
//   M2H   @ 50776 (8192)
//   HBUF  @ 58968 (8192)
//   M3H1  @ 67160 (512)
//   end   @ 67928
// Zero range (atomic-accumulated buffers): [2072, 67928)
// ---------------------------------------------------------------------------

__global__ __launch_bounds__(TPB) void stage1_kernel(
    const float* __restrict__ center, const float* __restrict__ corner,
    const float* __restrict__ normal,
    const float* __restrict__ spW1, const float* __restrict__ spb1,
    const float* __restrict__ spW2, const float* __restrict__ spb2,
    const float* __restrict__ Wc, const float* __restrict__ bc,
    const float* __restrict__ W3, const float* __restrict__ b3,
    const float* __restrict__ W4, const float* __restrict__ b4,
    const float* __restrict__ kck,
    const float* __restrict__ stW1, const float* __restrict__ stb1,
    const float* __restrict__ stW2, const float* __restrict__ stb2,
    float* __restrict__ ws) {
    int tid = threadIdx.x;
    int b = blockIdx.x;
    if (b < 8) {
        // ---- one face per block: FRC conv+mlp, kernel correlation, st MLP
        int f = b;
        __shared__ float sc[9], sn[3], sm[32], shh[64], sf[131], sh2[131];
        if (tid < 9) sc[tid] = corner[f * 9 + tid];
        if (tid < 3) { sn[tid] = normal[f * 3 + tid]; sf[tid] = normal[f * 3 + tid]; }
        __syncthreads();
        if (tid < 32) {                       // conv over 3 corner pairs, mean
            float acc = 0.f;
            for (int p = 0; p < 3; ++p) {
                const float* a  = &sc[3 * p];
                const float* b2 = &sc[3 * ((p + 1) % 3)];
                float d = bc[tid];
                for (int k = 0; k < 3; ++k)
                    d += a[k] * Wc[tid * 6 + k] + b2[k] * Wc[tid * 6 + 3 + k];
                acc += d;
            }
            sm[tid] = acc * (1.f / 3.f);
        }
        __syncthreads();
        if (tid < 64) {                       // frc hidden (32 -> 64), relu
            float h = b3[tid];
            for (int o = 0; o < 32; ++o) h = fmaf(sm[o], W3[o * 64 + tid], h);
            shh[tid] = fmaxf(h, 0.f);
        }
        if (tid < 64) {                       // kernel correlation -> sf[3+tid]
            float s = 0.f;
            for (int l = 0; l < 4; ++l) {
                float dx = sn[0] - kck[(tid * 4 + l) * 3 + 0];
                float dy = sn[1] - kck[(tid * 4 + l) * 3 + 1];
                float dz = sn[2] - kck[(tid * 4 + l) * 3 + 2];
                s += expf(-(dx * dx + dy * dy + dz * dz));
            }
            sf[3 + tid] = s * (1.f / 32.f);
        }
        __syncthreads();
        if (tid < 64) {                       // frc out (64 -> 64) -> sf[67+tid]
            float v = b4[tid];
            for (int k = 0; k < 64; ++k) v = fmaf(shh[k], W4[k * 64 + tid], v);
            sf[67 + tid] = v;
        }
        __syncthreads();
        if (tid < 131) {                      // st hidden, relu
            float a = stb1[tid];
            for (int k = 0; k < 131; ++k) a = fmaf(sf[k], stW1[k * 131 + tid], a);
            sh2[tid] = fmaxf(a, 0.f);
        }
        __syncthreads();
        if (tid < 131) {                      // st out -> Z
            float a = stb2[tid];
            for (int k = 0; k < 131; ++k) a = fmaf(sh2[k], stW2[k * 131 + tid], a);
            ws[1024 + f * 131 + tid] = a;
        }
    } else if (b < 12) {
        // ---- spatial chain: T1 = relu(center@spW1+b1) in LDS; y = T1@spW2+b2
        int bs = b - 8;
        __shared__ float sctr[24], st1[512];
        if (tid < 24) sctr[tid] = center[tid];
        __syncthreads();
        for (int j = tid; j < 512; j += TPB) {
            float a = spb1[j];
            for (int i = 0; i < 24; ++i) a = fmaf(sctr[i], spW1[i * 512 + j], a);
            st1[j] = fmaxf(a, 0.f);
        }
        __syncthreads();
        if (tid < 128) {
            int j = bs * 128 + tid;
            float a = spb2[j];
            for (int k = 0; k < 512; ++k) a = fmaf(st1[k], spW2[k * 512 + j], a);
            ws[512 + j] = a;                  // Y, direct write
        }
    } else {
        // ---- zero the atomic-accumulated region [2072, 67928)
        int zb = b - 12;                      // 0..31
        f4 z4 = {0.f, 0.f, 0.f, 0.f};
        f4* p = (f4*)(ws + 2072);
        int n4 = (67928 - 2072) / 4;          // 16464
        for (int i = zb * TPB + tid; i < n4; i += 32 * TPB) p[i] = z4;
    }
}

// ---------------------------------------------------------------------------
// Multi-GEMV (proven R10 body): split-K, HW f32 atomics onto zeroed bufs,
// bias in ci==0 chunk, fused relu/agg/maxpool staging, op5 = relu-sparse
// (deterministic ballot compaction), nt=1 = nontemporal weight stream
// (single-use weights only; reused weights stay cached).
// ---------------------------------------------------------------------------
struct Desc {
    const float* x; const float* W; float* out; const float* bias;
    const int* nb;
    int in_dim, out_dim, chunk, ntile, nchunk, nvec, xs, os;
    int op;        // 0 direct, 1 relu-in, 2 agg, 3 maxpool8, 4 copy, 5 relu-sparse
    int aggdim;
    int nt;
    int nblocks;
};
struct Descs { Desc d[3]; int nd; };

__global__ __launch_bounds__(TPB) void mg_kernel(Descs D) {
    int bid = blockIdx.x;
    int di = 0;
    while (di + 1 < D.nd && bid >= D.d[di].nblocks) { bid -= D.d[di].nblocks; ++di; }
    Desc d = D.d[di];
    int tid = threadIdx.x;
    if (d.op == 4) {                          // copy
        int i = bid * TPB + tid;
        int n4 = d.in_dim >> 2;
        if (i < n4) ((f4*)d.out)[i] = ((const f4*)d.x)[i];
        return;
    }
    __shared__ float sx[512];
    __shared__ float sval[512];
    __shared__ unsigned short sidx[512];
    __shared__ int segc[10];
    int per = d.ntile * d.nchunk;
    int vec = bid / per;
    int r = bid - vec * per;
    int ci = r / d.ntile;
    int tile = r - ci * d.ntile;
    const float* x = d.x + (size_t)vec * d.xs;
    float* out = d.out + (size_t)vec * d.os;
    int row0 = ci * d.chunk;
    int rows = min(d.chunk, d.in_dim - row0);
    for (int t = tid; t < rows; t += TPB) {
        int idx = row0 + t;
        float v;
        if (d.op == 2) {
            int i = idx / d.aggdim, k = idx - i * d.aggdim;
            const int* nb = d.nb + i * 3;
            v = 0.25f * (x[i * d.aggdim + k] + x[nb[0] * d.aggdim + k] +
                         x[nb[1] * d.aggdim + k] + x[nb[2] * d.aggdim + k]);
        } else if (d.op == 3) {
            v = x[idx];
#pragma unroll
            for (int f = 1; f < 8; ++f) v = fmaxf(v, x[f * d.in_dim + idx]);
        } else {
            v = x[idx];
            if (d.op == 1 || d.op == 5) v = fmaxf(v, 0.f);
        }
        sx[t] = v;
    }
    __syncthreads();

    if (d.op == 5) {
        // ---- deterministic ordered compaction of nonzero rows ----
        int wave = tid >> 6, lane = tid & 63;
        int nseg = (rows + 63) >> 6;
        for (int s = wave; s < nseg; s += 4) {
            int t = s * 64 + lane;
            bool p = (t < rows) && (sx[t] > 0.f);
            unsigned long long m = __ballot(p);
            if (lane == 0) segc[s] = __popcll(m);
        }
        __syncthreads();
        if (tid == 0) {
            int acc = 0;
            for (int s = 0; s < nseg; ++s) { int c = segc[s]; segc[s] = acc; acc += c; }
            segc[nseg] = acc;
        }
        __syncthreads();
        for (int s = wave; s < nseg; s += 4) {
            int t = s * 64 + lane;
            bool p = (t < rows) && (sx[t] > 0.f);
            unsigned long long m = __ballot(p);
            int rk = __popcll(m & ((1ull << lane) - 1ull));
            if (p) {
                int o = segc[s] + rk;
                sval[o] = sx[t];
                sidx[o] = (unsigned short)t;
            }
        }
        __syncthreads();
        int cnt = segc[nseg];
        int j = tile * (TPB * 4) + tid * 4;
        if (j >= d.out_dim) return;
        const float* wb = d.W + j;
        float ax = 0.f, ay = 0.f, az = 0.f, aw = 0.f;
        if (d.nt) {
#pragma unroll 8
            for (int t = 0; t < cnt; ++t) {
                float xv = sval[t];
                f4 w = __builtin_nontemporal_load(
                    (const f4*)(wb + (size_t)(row0 + (int)sidx[t]) * d.out_dim));
                ax = fmaf(xv, w[0], ax); ay = fmaf(xv, w[1], ay);
                az = fmaf(xv, w[2], az); aw = fmaf(xv, w[3], aw);
            }
        } else {
#pragma unroll 8
            for (int t = 0; t < cnt; ++t) {
                float xv = sval[t];
                f4 w = *(const f4*)(wb + (size_t)(row0 + (int)sidx[t]) * d.out_dim);
                ax = fmaf(xv, w[0], ax); ay = fmaf(xv, w[1], ay);
                az = fmaf(xv, w[2], az); aw = fmaf(xv, w[3], aw);
            }
        }
        if (ci == 0 && d.bias) {
            ax += d.bias[j]; ay += d.bias[j + 1];
            az += d.bias[j + 2]; aw += d.bias[j + 3];
        }
        unsafeAtomicAdd(&out[j + 0], ax);
        unsafeAtomicAdd(&out[j + 1], ay);
        unsafeAtomicAdd(&out[j + 2], az);
        unsafeAtomicAdd(&out[j + 3], aw);
        return;
    }

    int j = tile * (TPB * 4) + tid * 4;
    if (j >= d.out_dim) return;
    const float* wp = d.W + (size_t)row0 * d.out_dim + j;
    float ax = 0.f, ay = 0.f, az = 0.f, aw = 0.f;
    if (d.nt) {
#pragma unroll 16
        for (int t = 0; t < rows; ++t) {
            f4 w = __builtin_nontemporal_load((const f4*)wp);
            float xv = sx[t];
            ax = fmaf(xv, w[0], ax); ay = fmaf(xv, w[1], ay);
            az = fmaf(xv, w[2], az); aw = fmaf(xv, w[3], aw);
            wp += d.out_dim;
        }
    } else {
#pragma unroll 16
        for (int t = 0; t < rows; ++t) {
            f4 w = *(const f4*)wp;
            float xv = sx[t];
            ax = fmaf(xv, w[0], ax); ay = fmaf(xv, w[1], ay);
            az = fmaf(xv, w[2], az); aw = fmaf(xv, w[3], aw);
            wp += d.out_dim;
        }
    }
    if (ci == 0 && d.bias) {
        ax += d.bias[j]; ay += d.bias[j + 1]; az += d.bias[j + 2]; aw += d.bias[j + 3];
    }
    unsafeAtomicAdd(&out[j + 0], ax);
    unsafeAtomicAdd(&out[j + 1], ay);
    unsafeAtomicAdd(&out[j + 2], az);
    unsafeAtomicAdd(&out[j + 3], aw);
}

// tail: M3H2 = relu(M3H1)@m3_W2+b2 (redundant per block), logit j per block.
// 40 blocks x 256 threads; deterministic tree reduction.
__global__ __launch_bounds__(TPB) void tail_kernel(
    const float* __restrict__ m3h1, const float* __restrict__ W2,
    const float* __restrict__ b2, const float* __restrict__ W3,
    const float* __restrict__ b3, float* __restrict__ out) {
    __shared__ float s1[512], red[256];
    int tid = threadIdx.x, j = blockIdx.x;
    for (int k = tid; k < 512; k += TPB) s1[k] = fmaxf(m3h1[k], 0.f);
    __syncthreads();
    float a = b2[tid];
    for (int i = 0; i < 512; ++i) a = fmaf(s1[i], W2[i * 256 + tid], a);
    a = fmaxf(a, 0.f);                        // relu(M3H2[tid])
    red[tid] = a * W3[tid * 40 + j];
    __syncthreads();
    for (int s = 128; s > 0; s >>= 1) {
        if (tid < s) red[tid] += red[tid + s];
        __syncthreads();
    }
    if (tid == 0) out[j] = red[0] + b3[j];
}

// ---------------------------------------------------------------------------
static Desc gemv_desc(const float* x, const float* W, float* out, const float* bias,
                      int in, int outd, int chunk, int op,
                      int nvec = 1, int xs = 0, int os = 0,
                      const int* nb = nullptr, int aggdim = 0, int nt = 0) {
    Desc d{};
    d.x = x; d.W = W; d.out = out; d.bias = bias; d.nb = nb;
    d.in_dim = in; d.out_dim = outd; d.chunk = chunk;
    d.ntile = (outd + TPB * 4 - 1) / (TPB * 4);
    d.nchunk = (in + chunk - 1) / chunk;
    d.nvec = nvec; d.xs = xs; d.os = os;
    d.op = op; d.aggdim = aggdim; d.nt = nt;
    d.nblocks = d.ntile * d.nchunk * nvec;
    return d;
}
static Desc copy_desc(const float* src, float* dst, int n) {
    Desc d{};
    d.x = src; d.out = dst; d.in_dim = n; d.op = 4;
    d.nblocks = (n / 4 + TPB - 1) / TPB;
    return d;
}
static void mg1(hipStream_t s, Desc a) {
    Descs D{}; D.d[0] = a; D.nd = 1;
    mg_kernel<<<a.nblocks, TPB, 0, s>>>(D);
}
static void mg2(hipStream_t s, Desc a, Desc b) {
    Descs D{}; D.d[0] = a; D.d[1] = b; D.nd = 2;
    mg_kernel<<<a.nblocks + b.nblocks, TPB, 0, s>>>(D);
}
static void mg3(hipStream_t s, Desc a, Desc b, Desc c) {
    Descs D{}; D.d[0] = a; D.d[1] = b; D.d[2] = c; D.nd = 3;
    mg_kernel<<<a.nblocks + b.nblocks + c.nblocks, TPB, 0, s>>>(D);
}

extern "C" void kernel_launch(void* const* d_in, const int* in_sizes, int n_in,
                              void* d_out, int out_size, void* d_ws, size_t ws_size,
                              hipStream_t stream) {
    const float* center    = (const float*)d_in[0];
    const float* corner    = (const float*)d_in[1];
    const float* normal    = (const float*)d_in[2];
    const int*   neighbour = (const int*)  d_in[3];
    const float* sp_W1 = (const float*)d_in[4];
    const float* sp_b1 = (const float*)d_in[5];
    const float* sp_W2 = (const float*)d_in[6];
    const float* sp_b2 = (const float*)d_in[7];
    const float* frc_Wc = (const float*)d_in[8];
    const float* frc_bc = (const float*)d_in[9];
    const float* frc_W3 = (const float*)d_in[10];
    const float* frc_b3 = (const float*)d_in[11];
    const float* frc_W4 = (const float*)d_in[12];
    const float* frc_b4 = (const float*)d_in[13];
    const float* kc_kernel = (const float*)d_in[14];
    const float* st_W1 = (const float*)d_in[15];
    const float* st_b1 = (const float*)d_in[16];
    const float* st_W2 = (const float*)d_in[17];
    const float* st_b2 = (const float*)d_in[18];
    const float* c1_W1 = (const float*)d_in[19];
    const float* c1_b1 = (const float*)d_in[20];
    const float* c1_W2 = (const float*)d_in[21];
    const float* c1_b2 = (const float*)d_in[22];
    const float* a1_W3 = (const float*)d_in[23];
    const float* a1_b3 = (const float*)d_in[24];
    const float* a1_W4 = (const float*)d_in[25];
    const float* a1_b4 = (const float*)d_in[26];
    const float* c2_W1 = (const float*)d_in[27];
    const float* c2_b1 = (const float*)d_in[28];
    const float* c2_W2 = (const float*)d_in[29];
    const float* c2_b2 = (const float*)d_in[30];
    const float* a2_W3 = (const float*)d_in[31];
    const float* a2_b3 = (const float*)d_in[32];
    const float* a2_W4 = (const float*)d_in[33];
    const float* a2_b4 = (const float*)d_in[34];
    const float* nt_W1 = (const float*)d_in[35];
    const float* nt_b1 = (const float*)d_in[36];
    const float* nt_W2 = (const float*)d_in[37];
    const float* nt_b2 = (const float*)d_in[38];
    const float* m2_W1 = (const float*)d_in[39];
    const float* m2_b1 = (const float*)d_in[40];
    const float* m2_W2 = (const float*)d_in[41];
    const float* m2_b2 = (const float*)d_in[42];
    const float* m3_W1 = (const float*)d_in[43];
    const float* m3_b1 = (const float*)d_in[44];
    const float* m3_W2 = (const float*)d_in[45];
    const float* m3_b2 = (const float*)d_in[46];
    const float* m3_W3 = (const float*)d_in[47];
    const float* m3_b3 = (const float*)d_in[48];

    float* ws = (float*)d_ws;
    float* C1IN  = ws + 512;           // [Y(512) | Z(1048)]
    float* Z     = ws + 1024;
    float* C1H   = ws + 2072;
    float* OUT12 = ws + 3672;          // [out1 | out2]
    float* A1H   = ws + 7768;
    float* C2H   = ws + 11864;
    float* OUT34 = ws + 15960;         // [out3 | out4]
    float* A2H   = ws + 24152;
    float* NTH   = ws + 28248;
    float* OUT6  = ws + 36440;         // [out5 | out3c | out1c]
    float* M2H   = ws + 50776;
    float* HBUF  = ws + 58968;
    float* M3H1  = ws + 67160;

    // L1: faces + spatial chain + zeroing
    stage1_kernel<<<44, TPB, 0, stream>>>(center, corner, normal,
        sp_W1, sp_b1, sp_W2, sp_b2, frc_Wc, frc_bc, frc_W3, frc_b3,
        frc_W4, frc_b4, kc_kernel, st_W1, st_b1, st_W2, st_b2, ws);

    // L2: c1_W1 (x=[y|z]) + a1_W3 (agg1 inline from Z)  [NT, single-use]
    mg2(stream,
        gemv_desc(C1IN, c1_W1, C1H, c1_b1, 1560, 1600, 26, 0,
                  1, 0, 0, nullptr, 0, 1),
        gemv_desc(Z, a1_W3, A1H, a1_b3, 1048, 4096, 17, 2,
                  1, 0, 0, neighbour, 131, 1));
    // L3: c1_W2 (relu-sparse) + a1_W4 (relu-sparse)  [NT]
    mg2(stream,
        gemv_desc(C1H, c1_W2, OUT12, c1_b2, 1600, 2048, 28, 5,
                  1, 0, 0, nullptr, 0, 1),
        gemv_desc(A1H, a1_W4, OUT12 + 2048, a1_b4, 4096, 2048, 64, 5,
                  1, 0, 0, nullptr, 0, 1));
    // L4: c2_W1 + a2_W3 (agg2 inline from out2)  [NT]
    mg2(stream,
        gemv_desc(OUT12, c2_W1, C2H, c2_b1, 4096, 4096, 64, 0,
                  1, 0, 0, nullptr, 0, 1),
        gemv_desc(OUT12 + 2048, a2_W3, A2H, a2_b3, 2048, 4096, 32, 2,
                  1, 0, 0, neighbour, 256, 1));
    // L5: c2_W2 (sparse) + a2_W4 (sparse) + copy out1 -> OUT6 tail  [NT]
    mg3(stream,
        gemv_desc(C2H, c2_W2, OUT34, c2_b2, 4096, 4096, 64, 5,
                  1, 0, 0, nullptr, 0, 1),
        gemv_desc(A2H, a2_W4, OUT34 + 4096, a2_b4, 4096, 4096, 64, 5,
                  1, 0, 0, nullptr, 0, 1),
        copy_desc(OUT12, OUT6 + 12288, 2048));
    // L6: nt_W1 (8 faces, reused -> cached) + copy out3 -> OUT6 mid
    mg2(stream,
        gemv_desc(OUT34, nt_W1, NTH, nt_b1, 1024, 1024, 64, 0, 8, 1024, 1024),
        copy_desc(OUT34, OUT6 + 8192, 4096));
    // L7: nt_W2 -> out5 (relu-sparse, reused -> cached)
    mg1(stream,
        gemv_desc(NTH, nt_W2, OUT6, nt_b2, 1024, 1024, 64, 5, 8, 1024, 1024));
    // L8: m2_W1 (470 MB, dense, NT)
    mg1(stream, gemv_desc(OUT6, m2_W1, M2H, m2_b1, 14336, 8192, 448, 0,
                          1, 0, 0, nullptr, 0, 1));
    // L9: m2_W2 (268 MB, relu-sparse, NT)
    mg1(stream, gemv_desc(M2H, m2_W2, HBUF, m2_b2, 8192, 8192, 256, 5,
                          1, 0, 0, nullptr, 0, 1));
    // L10: m3_W1 with inline maxpool over 8 faces
    mg1(stream, gemv_desc(HBUF, m3_W1, M3H1, m3_b1, 1024, 512, 16, 3));
    // L11: fused m3_W2 + head (40 blocks, redundant M3H2 per block)
    tail_kernel<<<40, TPB, 0, stream>>>(M3H1, m3_W2, m3_b2, m3_W3, m3_b3,
                                        (float*)d_out);
}